// Round 19
// baseline (625.631 us; speedup 1.0000x reference)
//
#include <hip/hip_runtime.h>
#include <math.h>
#include <stdint.h>

#define B_ 2
#define N_ 2048
#define D_ 1024
#define H_ 16
#define HD_ 64
#define M_ (B_ * N_)   // 4096
#define NBLK 768

typedef __bf16 bf16x8 __attribute__((ext_vector_type(8)));
typedef float f32x4 __attribute__((ext_vector_type(4)));

__device__ __forceinline__ ushort bfbits(float f) {
    __bf16 h = (__bf16)f;
    return __builtin_bit_cast(ushort, h);
}

// async global->LDS, 16B per lane; LDS dest = wave-uniform base + lane*16
__device__ __forceinline__ void glds16(const ushort* g, ushort* l) {
    __builtin_amdgcn_global_load_lds(
        (const __attribute__((address_space(1))) uint32_t*)g,
        (__attribute__((address_space(3))) uint32_t*)l, 16, 0, 0);
}

// grid-wide barrier: all NBLK blocks co-resident by capacity construction
// (LDS 40960B -> 4 blocks/CU cap, we need 3; 12 waves/CU <= 32; VGPR<=168).
// Device-scope atomics + threadfence per G16 (cross-XCD L2 non-coherence).
__device__ __forceinline__ void gridbar(uint32_t* ctr) {
    __syncthreads();
    __threadfence();                       // release: drain our writes
    if (threadIdx.x == 0) {
        atomicAdd(ctr, 1u);
        while (atomicAdd(ctr, 0u) < NBLK) __builtin_amdgcn_s_sleep(8);
    }
    __syncthreads();
    __threadfence();                       // acquire: invalidate stale lines
}

// ---------------------------------------------------------------------------
// MFMA GEMM mainloop (m97 structure): 128x128 tile, BK=32, linear LDS
// [128][32] bf16 staged via global_load_lds w=16, both-sides XOR swizzle.
// ---------------------------------------------------------------------------
#define BK 32

__device__ __forceinline__ void gemm_tile(const ushort* __restrict__ A,
                                          const ushort* __restrict__ Bt,
                                          int K, int tileM, int tileN,
                                          ushort* As, ushort* Bs,
                                          f32x4 acc[4][4]) {
    const int t = threadIdx.x;
    const int l = t & 63;
    const int w = __builtin_amdgcn_readfirstlane(t >> 6);
    const int wr = w >> 1, wc = w & 1;
    const int li = l & 15, lg = l >> 4;
    const int lr = l >> 2;
    const int colu = (((l & 3) ^ (lr & 3)) << 3);   // inverse-swizzled src col
    const int swz = (li & 3) << 3;                   // read-side xor

    for (int k0 = 0; k0 < K; k0 += BK) {
        __syncthreads();
        #pragma unroll
        for (int it = 0; it < 2; ++it) {
            const int c2 = it * 4 + w;
            const int row = c2 * 16 + lr;
            glds16(&A[(size_t)(tileM + row) * K + k0 + colu], &As[c2 * 512]);
            glds16(&Bt[(size_t)(tileN + row) * K + k0 + colu], &Bs[c2 * 512]);
        }
        __syncthreads();
        bf16x8 a[4], b[4];
        #pragma unroll
        for (int m = 0; m < 4; ++m)
            a[m] = *(const bf16x8*)&As[(wr * 64 + m * 16 + li) * 32 + ((lg << 3) ^ swz)];
        #pragma unroll
        for (int n = 0; n < 4; ++n)
            b[n] = *(const bf16x8*)&Bs[(wc * 64 + n * 16 + li) * 32 + ((lg << 3) ^ swz)];
        #pragma unroll
        for (int m = 0; m < 4; ++m)
            #pragma unroll
            for (int n = 0; n < 4; ++n)
                acc[m][n] = __builtin_amdgcn_mfma_f32_16x16x32_bf16(a[m], b[n], acc[m][n], 0, 0, 0);
    }
}

// attention helpers (R11-verified, best-known config)
__device__ __forceinline__ void qk_mfma(f32x4 st[4], const ushort* Kb,
                                        const bf16x8 bq[2],
                                        int li, int lg, int rswz) {
    #pragma unroll
    for (int c = 0; c < 4; ++c) {
        st[c] = (f32x4){0.f, 0.f, 0.f, 0.f};
        #pragma unroll
        for (int tk = 0; tk < 2; ++tk) {
            bf16x8 kf = *(const bf16x8*)&Kb[(c * 16 + li) * 64 + (((tk * 4 + lg) ^ rswz) * 8)];
            st[c] = __builtin_amdgcn_mfma_f32_16x16x32_bf16(kf, bq[tk], st[c], 0, 0, 0);
        }
    }
}

__device__ __forceinline__ void softmax_pv(f32x4 st[4], const ushort* Vb,
                                           bool masked, int jkb, int qg,
                                           int li, int lg, int rswz,
                                           ushort* PsW, f32x4& lacc,
                                           f32x4 od[4], bf16x8 ones) {
    if (masked) {
        #pragma unroll
        for (int c = 0; c < 4; ++c)
            #pragma unroll
            for (int r = 0; r < 4; ++r) {
                const int kgl = jkb * 64 + c * 16 + lg * 4 + r;
                if (kgl > qg) st[c][r] = -INFINITY;
            }
    }
    const int sw = li & 7;
    #pragma unroll
    for (int c = 0; c < 4; ++c) {
        float p0 = exp2f(st[c][0]);
        float p1 = exp2f(st[c][1]);
        float p2 = exp2f(st[c][2]);
        float p3 = exp2f(st[c][3]);
        uint32_t w0, w1;
        asm("v_cvt_pk_bf16_f32 %0, %1, %2" : "=v"(w0) : "v"(p0), "v"(p1));
        asm("v_cvt_pk_bf16_f32 %0, %1, %2" : "=v"(w1) : "v"(p2), "v"(p3));
        uint2 pk; pk.x = w0; pk.y = w1;
        *(uint2*)&PsW[li * 64 + (((c * 2 + (lg >> 1)) ^ sw) << 3) + ((lg & 1) << 2)] = pk;
    }
    #pragma unroll
    for (int tj = 0; tj < 2; ++tj) {
        bf16x8 pa = *(const bf16x8*)&PsW[li * 64 + (((tj * 4 + lg) ^ sw) << 3)];
        lacc = __builtin_amdgcn_mfma_f32_16x16x32_bf16(pa, ones, lacc, 0, 0, 0);
        #pragma unroll
        for (int db = 0; db < 4; ++db) {
            bf16x8 bv = *(const bf16x8*)&Vb[(db * 16 + li) * 64 + (((tj * 4 + lg) ^ rswz) * 8)];
            od[db] = __builtin_amdgcn_mfma_f32_16x16x32_bf16(pa, bv, od[db], 0, 0, 0);
        }
    }
}

#define QSCALE 0.180336880f   // 1/sqrt(64) * log2(e)

// ---------------------------------------------------------------------------
// Fused persistent kernel: prep -> qkv -> attn -> out with grid barriers.
// LDS pool = 40960 B union:
//   prep: float T[32][33] (4.2K)
//   qkv:  As 8K | Bs 8K (mainloop), then Eps[128][130] 33.3K (overlay, after
//         a barrier)
//   attn: Ks 2x8K + Vs 2x8K + Ps 4x2K = 40K
//   out:  As 8K | Bs 8K
// ---------------------------------------------------------------------------
__global__ __launch_bounds__(256, 3) void fused(
    const float* __restrict__ x,
    const float* __restrict__ W0, const float* __restrict__ W1,
    const float* __restrict__ W2, const float* __restrict__ W3,
    const float* __restrict__ bo,
    ushort* __restrict__ xb, ushort* __restrict__ Wt,
    ushort* __restrict__ qb, ushort* __restrict__ kb,
    ushort* __restrict__ vtb, ushort* __restrict__ ctx,
    float* __restrict__ outp, uint32_t* __restrict__ ctr)
{
    __shared__ ushort pool[20480];   // 40960 B
    const int blk = blockIdx.x;
    const int t = threadIdx.x;

    // ================= phase 0: prep (grid-stride, 8192 units) ============
    {
        float* T = (float*)pool;     // [32][33]
        for (int u = blk; u < 8192; u += NBLK) {
            if (u < 4096) {
                int i = u * 256 + t;
                float4 v = ((const float4*)x)[i];
                ushort4 o;
                o.x = bfbits(v.x); o.y = bfbits(v.y); o.z = bfbits(v.z); o.w = bfbits(v.w);
                ((ushort4*)xb)[i] = o;
            } else {
                const int id = u - 4096;
                const int z = id >> 10;
                const int k0 = (id & 31) * 32, n0 = ((id >> 5) & 31) * 32;
                const float* W = (z == 0) ? W0 : (z == 1) ? W1 : (z == 2) ? W2 : W3;
                ushort* outw = Wt + (size_t)z * D_ * D_;
                __syncthreads();   // T reuse across units
                {
                    int kl = t >> 3, nl = (t & 7) * 4;
                    float4 v = *(const float4*)&W[(size_t)(k0 + kl) * D_ + n0 + nl];
                    T[kl * 33 + nl] = v.x; T[kl * 33 + nl + 1] = v.y;
                    T[kl * 33 + nl + 2] = v.z; T[kl * 33 + nl + 3] = v.w;
                }
                __syncthreads();
                {
                    int nl = t >> 3, k4 = (t & 7) * 4;
                    ushort4 o;
                    o.x = bfbits(T[(k4 + 0) * 33 + nl]); o.y = bfbits(T[(k4 + 1) * 33 + nl]);
                    o.z = bfbits(T[(k4 + 2) * 33 + nl]); o.w = bfbits(T[(k4 + 3) * 33 + nl]);
                    *(ushort4*)&outw[(size_t)(n0 + nl) * D_ + k0 + k4] = o;
                }
            }
        }
    }
    gridbar(&ctr[0]);

    // ================= phase 1: qkv GEMM (tile = blk, 768 tiles) ==========
    {
        ushort* As = pool;
        ushort* Bs = pool + 4096;
        f32x4 acc[4][4];
        #pragma unroll
        for (int m = 0; m < 4; ++m)
            #pragma unroll
            for (int n = 0; n < 4; ++n)
                acc[m][n] = (f32x4){0.f, 0.f, 0.f, 0.f};

        const int wg = (blk & 7) * 96 + (blk >> 3);   // XCD swizzle
        const int tileM = (wg & 31) * 128;
        const int yy = wg >> 5;
        const int wsel = yy >> 3;
        const int tileN = (yy & 7) * 128;
        const ushort* Bmat = Wt + (size_t)wsel * D_ * D_;

        gemm_tile(xb, Bmat, D_, tileM, tileN, As, Bs, acc);

        const int l = t & 63, w = t >> 6;
        const int wr = w >> 1, wc = w & 1;
        const int li = l & 15, lg = l >> 4;
        const float scale = (wsel == 0) ? QSCALE : 1.0f;

        __syncthreads();             // all As/Bs reads done before Eps overlay
        ushort* Eps = pool;          // [128][130] overlay
        if (wsel < 2) {
            #pragma unroll
            for (int m = 0; m < 4; ++m)
                #pragma unroll
                for (int n = 0; n < 4; ++n)
                    #pragma unroll
                    for (int r = 0; r < 4; ++r)
                        Eps[(wr * 64 + m * 16 + lg * 4 + r) * 130 + wc * 64 + n * 16 + li] =
                            bfbits(acc[m][n][r] * scale);
        } else {
            #pragma unroll
            for (int m = 0; m < 4; ++m)
                #pragma unroll
                for (int n = 0; n < 4; ++n)
                    #pragma unroll
                    for (int r = 0; r < 4; ++r)
                        Eps[(wc * 64 + n * 16 + li) * 130 + wr * 64 + m * 16 + lg * 4 + r] =
                            bfbits(acc[m][n][r]);
        }
        __syncthreads();

        const int rr = t >> 3;
        const int cb = (t & 7) * 16;
        if (wsel < 2) {
            ushort* outq = (wsel == 0) ? qb : kb;
            #pragma unroll
            for (int it = 0; it < 4; ++it) {
                const int row = it * 32 + rr;
                uint4 v0 = *(const uint4*)&Eps[row * 130 + cb];
                uint4 v1 = *(const uint4*)&Eps[row * 130 + cb + 8];
                size_t base = (size_t)(tileM + row) * D_ + tileN + cb;
                *(uint4*)&outq[base] = v0;
                *(uint4*)&outq[base + 8] = v1;
            }
        } else {
            const int b = tileM >> 11;
            const int n0 = (tileM & (N_ - 1)) + cb;
            #pragma unroll
            for (int it = 0; it < 4; ++it) {
                const int row = it * 32 + rr;
                const int gcol = tileN + row;
                const int h = gcol >> 6, hd = gcol & 63;
                uint4 v0 = *(const uint4*)&Eps[row * 130 + cb];
                uint4 v1 = *(const uint4*)&Eps[row * 130 + cb + 8];
                size_t base = ((size_t)(b * H_ + h) * HD_ + hd) * N_ + n0;
                *(uint4*)&vtb[base] = v0;
                *(uint4*)&vtb[base + 8] = v1;
            }
        }
    }
    gridbar(&ctr[1]);

    // ================= phase 2: attention (blocks 0..511) =================
    if (blk < 512) {
        ushort* Ks0 = pool;                  // [2][4096]
        ushort* Vs0 = pool + 8192;           // [2][4096]
        ushort* Ps0 = pool + 16384;          // [4][1024]

        const int l = t & 63;
        const int w = __builtin_amdgcn_readfirstlane(t >> 6);
        const int li = l & 15, lg = l >> 4;
        const int f = blk;
        const int bh = ((f & 7) << 2) | ((f >> 3) & 3);
        const int p = f >> 5;
        const int qtA = p, qtB = 31 - p;
        const int b = bh >> 4, h = bh & 15;

        const ushort* Qg = qb + ((size_t)b * N_) * D_ + h * 64;
        const ushort* Kg = kb + ((size_t)b * N_) * D_ + h * 64;
        const ushort* Vg = vtb + (size_t)bh * HD_ * N_;
        ushort* PsW = Ps0 + w * 1024;

        const int r8 = l >> 3;
        const int soff = ((l & 7) ^ r8) * 8;
        const int rswz = li & 7;

        const int qgA = qtA * 64 + w * 16 + li;
        const int qgB = qtB * 64 + w * 16 + li;

        bf16x8 bqA[2], bqB[2];
        #pragma unroll
        for (int tk = 0; tk < 2; ++tk) {
            bqA[tk] = *(const bf16x8*)&Qg[(size_t)qgA * D_ + tk * 32 + lg * 8];
            bqB[tk] = *(const bf16x8*)&Qg[(size_t)qgB * D_ + tk * 32 + lg * 8];
        }

        bf16x8 ones;
        #pragma unroll
        for (int i = 0; i < 8; ++i) ones[i] = (__bf16)1.0f;

        f32x4 odA[4], odB[4];
        #pragma unroll
        for (int db = 0; db < 4; ++db) {
            odA[db] = (f32x4){0.f, 0.f, 0.f, 0.f};
            odB[db] = (f32x4){0.f, 0.f, 0.f, 0.f};
        }
        f32x4 laccA = (f32x4){0.f, 0.f, 0.f, 0.f};
        f32x4 laccB = (f32x4){0.f, 0.f, 0.f, 0.f};

        #pragma unroll
        for (int i = 0; i < 2; ++i) {
            const int seg = w + i * 4;
            const int row = seg * 8 + r8;
            glds16(&Kg[(size_t)row * D_ + soff], &Ks0[seg * 512]);
            glds16(&Vg[(size_t)row * N_ + soff], &Vs0[seg * 512]);
        }
        __syncthreads();

        int cur = 0;
        for (int kbi = 0; kbi <= qtB; ++kbi) {
            if (kbi < qtB) {
                #pragma unroll
                for (int i = 0; i < 2; ++i) {
                    const int seg = w + i * 4;
                    const int row = seg * 8 + r8;
                    glds16(&Kg[(size_t)((kbi + 1) * 64 + row) * D_ + soff],
                           &Ks0[(cur ^ 1) * 4096 + seg * 512]);
                    glds16(&Vg[(size_t)row * N_ + (kbi + 1) * 64 + soff],
                           &Vs0[(cur ^ 1) * 4096 + seg * 512]);
                }
            }
            {
                f32x4 st[4];
                qk_mfma(st, Ks0 + cur * 4096, bqB, li, lg, rswz);
                softmax_pv(st, Vs0 + cur * 4096, kbi == qtB, kbi, qgB, li, lg, rswz,
                           PsW, laccB, odB, ones);
            }
            if (kbi <= qtA) {
                f32x4 st[4];
                qk_mfma(st, Ks0 + cur * 4096, bqA, li, lg, rswz);
                softmax_pv(st, Vs0 + cur * 4096, kbi == qtA, kbi, qgA, li, lg, rswz,
                           PsW, laccA, odA, ones);
            }
            __syncthreads();
            cur ^= 1;
        }

        #pragma unroll
        for (int r = 0; r < 4; ++r) {
            const float invA = 1.f / laccA[r];
            const int growA = qtA * 64 + w * 16 + lg * 4 + r;
            #pragma unroll
            for (int db = 0; db < 4; ++db)
                ctx[((size_t)(b * N_ + growA)) * D_ + h * 64 + db * 16 + li] = bfbits(odA[db][r] * invA);
            const float invB = 1.f / laccB[r];
            const int growB = qtB * 64 + w * 16 + lg * 4 + r;
            #pragma unroll
            for (int db = 0; db < 4; ++db)
                ctx[((size_t)(b * N_ + growB)) * D_ + h * 64 + db * 16 + li] = bfbits(odB[db][r] * invB);
        }
    }
    gridbar(&ctr[2]);

    // ================= phase 3: output GEMM (blocks 0..255) ===============
    if (blk < 256) {
        ushort* As = pool;
        ushort* Bs = pool + 4096;
        f32x4 acc[4][4];
        #pragma unroll
        for (int m = 0; m < 4; ++m)
            #pragma unroll
            for (int n = 0; n < 4; ++n)
                acc[m][n] = (f32x4){0.f, 0.f, 0.f, 0.f};

        const int wg = (blk & 7) * 32 + (blk >> 3);   // XCD swizzle
        const int tileM = (wg & 31) * 128;
        const int tileN = (wg >> 5) * 128;
        const ushort* Bmat = Wt + (size_t)3 * D_ * D_;

        gemm_tile(ctx, Bmat, D_, tileM, tileN, As, Bs, acc);

        const int l = t & 63, w = t >> 6;
        const int wr = w >> 1, wc = w & 1;
        const int li = l & 15, lg = l >> 4;
        #pragma unroll
        for (int n = 0; n < 4; ++n) {
            float bias = bo[tileN + wc * 64 + n * 16 + li];
            #pragma unroll
            for (int m = 0; m < 4; ++m)
                #pragma unroll
                for (int r = 0; r < 4; ++r) {
                    int grow = tileM + wr * 64 + m * 16 + lg * 4 + r;
                    int gcol = tileN + wc * 64 + n * 16 + li;
                    outp[(size_t)grow * D_ + gcol] = acc[m][n][r] + bias;
                }
        }
    }
}

// ---------------------------------------------------------------------------
extern "C" void kernel_launch(void* const* d_in, const int* in_sizes, int n_in,
                              void* d_out, int out_size, void* d_ws, size_t ws_size,
                              hipStream_t stream) {
    (void)in_sizes; (void)n_in; (void)out_size; (void)ws_size;
    const float* x  = (const float*)d_in[0];
    const float* Wq = (const float*)d_in[1];
    const float* Wk = (const float*)d_in[2];
    const float* Wv = (const float*)d_in[3];
    const float* Wo = (const float*)d_in[4];
    const float* bo = (const float*)d_in[5];
    float* outp = (float*)d_out;

    ushort* xb  = (ushort*)d_ws;                       //  8 MB [M][D]
    ushort* Wt  = xb + (size_t)M_ * D_;                //  8 MB (4x 1024^2, n-major)
    ushort* qb  = Wt + (size_t)4 * D_ * D_;            //  8 MB [M][D]
    ushort* kb  = qb + (size_t)M_ * D_;                //  8 MB [M][D]
    ushort* vtb = kb + (size_t)M_ * D_;                //  8 MB [B,H,HD,N]
    ushort* ctx = vtb + (size_t)M_ * D_;               //  8 MB [M][D]
    uint32_t* ctr = (uint32_t*)((char*)d_ws + (size_t)48 * 1024 * 1024);

    hipMemsetAsync(ctr, 0, 3 * sizeof(uint32_t), stream);
    fused<<<dim3(NBLK), 256, 0, stream>>>(x, Wq, Wk, Wv, Wo, bo,
                                          xb, Wt, qb, kb, vtb, ctx, outp, ctr);
}